// Round 14
// baseline (114.477 us; speedup 1.0000x reference)
//
#include <hip/hip_runtime.h>
#include <stdint.h>

typedef __bf16 bf16;
typedef bf16 bf16x8 __attribute__((ext_vector_type(8)));
typedef float f32x4 __attribute__((ext_vector_type(4)));
typedef float f32x16 __attribute__((ext_vector_type(16)));
typedef uint32_t u32;
typedef uint16_t u16;
typedef int64_t i64;
typedef u32 u32x4 __attribute__((ext_vector_type(4)));

#define BATCH 4
#define NSEQ  4096
#define DHEAD 128
#define GROUPS 8                  // kv-split groups = waves per block (2 waves/SIMD)
#define KB    32
#define KVSPAN (NSEQ/GROUPS)      // 512
#define NITER  (KVSPAN/KB)        // 16
#define NKT    (NSEQ/KB)          // 128 tiles per batch
#define KT8_B  4096               // fp8 K tile bytes
#define VT_B   8192               // bf16 V^T tile bytes
#define LOG2E 1.44269504088896340736f
#define OROW  136                 // epilogue Obuf row stride (floats)

__device__ __forceinline__ u16 f2bf(float f) {
    u32 u = __builtin_bit_cast(u32, f);
    u += 0x7fff + ((u >> 16) & 1);   // RNE
    return (u16)(u >> 16);
}

// f32 -> OCP e4m3fn, RNE
__device__ __forceinline__ u32 f2fp8(float f) {
    u32 u = __builtin_bit_cast(u32, f);
    u32 sgn = (u >> 24) & 0x80;
    float af = fabsf(f);
    if (af < 0x1.0p-6f) {
        u32 m = (u32)rintf(af * 512.0f);
        return sgn | m;
    }
    u32 au = u & 0x7FFFFFFF;
    au += 0x7FFFF + ((au >> 20) & 1);
    u32 e = au >> 23;
    if (e > 135) { e = 135; au = (135u << 23) | (6u << 20); }
    u32 m3 = (au >> 20) & 7;
    return sgn | ((e - 120) << 3) | m3;
}

// |e4m3fn| -> f32 (sign dropped; used only for squaring)
__device__ __forceinline__ float dfp8(u32 c) {
    u32 a = c & 0x7F;
    u32 e = a >> 3, m = a & 7;
    float norm = __builtin_bit_cast(float, ((e + 120) << 23) | (m << 20));
    float den  = (float)m * 0x1.0p-9f;
    return e ? norm : den;
}

// ---------------- prep: fp32 x -> fp8-packed Kp8 (K/Q fragments) + bf16 Vp ----------------
__global__ __launch_bounds__(256) void prep_kernel(const float* __restrict__ x,
                                                   char* __restrict__ Kp8,
                                                   char* __restrict__ Vp) {
    __shared__ float lds[32][132];
    int bid = blockIdx.x;            // 512 blocks = b(4) x kt(128)
    int b = bid >> 7, kt = bid & 127;
    int t = threadIdx.x;
    const float* xt = x + ((size_t)b * NSEQ + kt * 32) * DHEAD;
    #pragma unroll
    for (int j = 0; j < 16; j++) {
        int idx = t + j * 256;
        int r = idx >> 7, c = idx & 127;
        lds[r][c] = xt[r * DHEAD + c];
    }
    __syncthreads();
    // K fp8 slot: one 16B slot per thread (t = dcp*64 + hh*32 + r)
    {
        int dcp = t >> 6, hh = (t >> 5) & 1, r = t & 31;
        u32 w[4];
        #pragma unroll
        for (int b8 = 0; b8 < 2; b8++) {
            #pragma unroll
            for (int half = 0; half < 2; half++) {
                u32 acc = 0;
                #pragma unroll
                for (int i = 0; i < 4; i++) {
                    float f = lds[r][dcp * 32 + b8 * 16 + hh * 8 + half * 4 + i];
                    acc |= f2fp8(f) << (8 * i);
                }
                w[b8 * 2 + half] = acc;
            }
        }
        u32x4 wv = {w[0], w[1], w[2], w[3]};
        *(u32x4*)(void*)(Kp8 + (size_t)(b * NKT + kt) * KT8_B + t * 16) = wv;
    }
    // V bf16 slots: two per thread
    char* vout = Vp + (size_t)(b * NKT + kt) * VT_B;
    #pragma unroll
    for (int j = 0; j < 2; j++) {
        int slot = t + j * 256;
        int s = slot >> 8, db = (slot >> 6) & 3, hh = (slot >> 5) & 1, r = slot & 31;
        u16 tmp[8];
        #pragma unroll
        for (int i = 0; i < 8; i++) tmp[i] = f2bf(lds[s * 16 + hh * 8 + i][db * 32 + r]);
        *(bf16x8*)(void*)(vout + slot * 16) = *(const bf16x8*)(const void*)tmp;
    }
}

// ---------------- flash attention: fp8 QK^T, bf16 PV, 2 waves/SIMD ----------------
// 256 blocks x 8 waves (512 thr): 8 kv-groups x 16 tiles; each wave computes BOTH
// 32-row q-tiles (K/V register reuse x2 -> per-CU traffic unchanged vs r13), and
// 2 waves/SIMD overlap one wave's softmax VALU with the other's MFMA/loads.
__device__ __forceinline__ void load_k8(u32x4 (&k)[4], const char* p) {
    #pragma unroll
    for (int j = 0; j < 4; j++)
        k[j] = *(const u32x4*)(const void*)(p + j * 1024);
}

__device__ __forceinline__ void load_v(bf16x8 (&v)[8], const char* p) {
    #pragma unroll
    for (int db = 0; db < 4; db++) {
        v[2*db]   = *(const bf16x8*)(const void*)(p + db * 1024);          // s=0
        v[2*db+1] = *(const bf16x8*)(const void*)(p + 4096 + db * 1024);   // s=1
    }
}

__device__ __forceinline__ u32 packbf(float lo, float hi) {
    return __builtin_amdgcn_perm(__builtin_bit_cast(u32, hi),
                                 __builtin_bit_cast(u32, lo), 0x07060302u);
}

__device__ __forceinline__ void attn_tile(const u32x4 (&k8)[4], const bf16x8 (&vf)[8],
                                          const u32x4 (&q8)[4], f32x16 (&acc)[4],
                                          float diagL, float& lsum) {
    f32x16 zz = {0.f,0.f,0.f,0.f,0.f,0.f,0.f,0.f,0.f,0.f,0.f,0.f,0.f,0.f,0.f,0.f};
    // QK^T: 8 fp8 MFMAs (K=16 each), single accumulate chain
    f32x16 s = zz;
    #pragma unroll
    for (int j = 0; j < 4; j++) {
        i64 klo = (i64)k8[j][0] | ((i64)k8[j][1] << 32);
        i64 khi = (i64)k8[j][2] | ((i64)k8[j][3] << 32);
        i64 qlo = (i64)q8[j][0] | ((i64)q8[j][1] << 32);
        i64 qhi = (i64)q8[j][2] | ((i64)q8[j][3] << 32);
        s = __builtin_amdgcn_mfma_f32_32x32x16_fp8_fp8(klo, qlo, s, 0, 0, 0);
        s = __builtin_amdgcn_mfma_f32_32x32x16_fp8_fp8(khi, qhi, s, 0, 0, 0);
    }

    // fixed-shift softmax weights: p = 2^(s*log2e - diagL)
    float p[16];
    #pragma unroll
    for (int i = 0; i < 16; i++)
        p[i] = __builtin_amdgcn_exp2f(s[i] * LOG2E - diagL);
    float ss[8];
    #pragma unroll
    for (int i = 0; i < 8; i++) ss[i] = p[i] + p[i + 8];
    #pragma unroll
    for (int i = 0; i < 4; i++) ss[i] += ss[i + 4];
    lsum += (ss[0] + ss[1]) + (ss[2] + ss[3]);

    // P -> bf16 pairs (v_perm trunc) -> permlane32_swap -> PV B-fragments
    u32 c01   = packbf(p[0],  p[1]);
    u32 c23   = packbf(p[2],  p[3]);
    u32 c89   = packbf(p[4],  p[5]);
    u32 c1011 = packbf(p[6],  p[7]);
    u32 cA    = packbf(p[8],  p[9]);
    u32 cB    = packbf(p[10], p[11]);
    u32 cC    = packbf(p[12], p[13]);
    u32 cD    = packbf(p[14], p[15]);
    auto sA = __builtin_amdgcn_permlane32_swap(c01, c89,   false, false);
    auto sB = __builtin_amdgcn_permlane32_swap(c23, c1011, false, false);
    auto sC = __builtin_amdgcn_permlane32_swap(cA, cC,     false, false);
    auto sD = __builtin_amdgcn_permlane32_swap(cB, cD,     false, false);
    bf16x8 pb0 = __builtin_bit_cast(bf16x8, (u32x4){sA[0], sB[0], sA[1], sB[1]});
    bf16x8 pb1 = __builtin_bit_cast(bf16x8, (u32x4){sC[0], sD[0], sC[1], sD[1]});

    // PV: out^T += V^T . P^T, 4 d-blocks x 2 k-steps (bf16)
    #pragma unroll
    for (int db = 0; db < 4; db++) {
        acc[db] = __builtin_amdgcn_mfma_f32_32x32x16_bf16(vf[2*db],     pb0, acc[db], 0, 0, 0);
        acc[db] = __builtin_amdgcn_mfma_f32_32x32x16_bf16(vf[2*db + 1], pb1, acc[db], 0, 0, 0);
    }
}

__global__ __launch_bounds__(512, 1) void attn_kernel(const char* __restrict__ Kp8,
                                                      const char* __restrict__ Vp,
                                                      float* __restrict__ out) {
    __shared__ float Obuf[64 * OROW];          // 34.8 KB epilogue combine buffer
    __shared__ float Lx[GROUPS][64];

    int bid = blockIdx.x;            // 256 blocks, 1/CU (8 waves = 2/SIMD)
    int xcd = bid & 7, pos = bid >> 3;
    int b    = xcd >> 1;             // 2 XCDs per batch -> batch packed data L2-resident
    int qblk = pos + ((xcd & 1) << 5);

    int t = threadIdx.x;
    int w = t >> 6, l = t & 63;
    int grp = w;                     // each wave is one kv-group, owns all 64 q-rows
    int r  = l & 31;                 // lane row (m/n index)
    int hh = l >> 5;                 // k-half

    const char* Kpb = Kp8 + (size_t)b * NKT * KT8_B + (size_t)l * 16;
    const char* Vpb = Vp  + (size_t)b * NKT * VT_B  + (size_t)l * 16;

    // Q fragments for both q-tiles (fp8, same packing as K)
    u32x4 q0[4], q1[4];
    load_k8(q0, Kpb + (size_t)(qblk * 2)     * KT8_B);
    load_k8(q1, Kpb + (size_t)(qblk * 2 + 1) * KT8_B);

    // diag shift C = fp8-exact ||q||^2 (decode-square-sum own half + cross-half add)
    float dsq0 = 0.f, dsq1 = 0.f;
    #pragma unroll
    for (int j = 0; j < 4; j++) {
        #pragma unroll
        for (int wv = 0; wv < 4; wv++) {
            u32 w0 = q0[j][wv], w1 = q1[j][wv];
            #pragma unroll
            for (int by = 0; by < 4; by++) {
                float v0 = dfp8(w0 >> (8 * by));
                float v1 = dfp8(w1 >> (8 * by));
                dsq0 += v0 * v0;
                dsq1 += v1 * v1;
            }
        }
    }
    dsq0 += __shfl_xor(dsq0, 32);
    dsq1 += __shfl_xor(dsq1, 32);
    float diagL0 = dsq0 * LOG2E;
    float diagL1 = dsq1 * LOG2E;

    f32x16 zz = {0.f,0.f,0.f,0.f,0.f,0.f,0.f,0.f,0.f,0.f,0.f,0.f,0.f,0.f,0.f,0.f};
    f32x16 acc0[4], acc1[4];         // out^T: d = db*32+(reg&3)+8*(reg>>2)+4*hh, q = qt*32+r
    #pragma unroll
    for (int i = 0; i < 4; i++) { acc0[i] = zz; acc1[i] = zz; }
    float lsum0 = 0.f, lsum1 = 0.f;

    int kt0 = grp * NITER;           // this group's 16 tiles
    u32x4 kA[4], kB[4];
    bf16x8 vA[8], vB[8];
    load_k8(kA, Kpb + (size_t)kt0 * KT8_B);
    load_v(vA, Vpb + (size_t)kt0 * VT_B);
    for (int it = 0; it < NITER; it += 2) {
        int kt = kt0 + it;
        load_k8(kB, Kpb + (size_t)(kt + 1) * KT8_B);          // prefetch K,V tile it+1
        load_v(vB, Vpb + (size_t)(kt + 1) * VT_B);
        attn_tile(kA, vA, q0, acc0, diagL0, lsum0);           // K/V reused for both q-tiles
        attn_tile(kA, vA, q1, acc1, diagL1, lsum1);
        if (it + 2 < NITER) {
            load_k8(kA, Kpb + (size_t)(kt + 2) * KT8_B);      // prefetch K,V tile it+2
            load_v(vA, Vpb + (size_t)(kt + 2) * VT_B);
        }
        attn_tile(kB, vB, q0, acc0, diagL0, lsum0);
        attn_tile(kB, vB, q1, acc1, diagL1, lsum1);
    }

    // ---- combine 8 kv-groups (shared shift per row -> plain sums) ----
    lsum0 += __shfl_xor(lsum0, 32);
    lsum1 += __shfl_xor(lsum1, 32);
    if (l < 32) { Lx[grp][r] = lsum0; Lx[grp][32 + r] = lsum1; }
    __syncthreads();

    #pragma unroll
    for (int j = 0; j < GROUPS; j++) {
        if (grp == j) {
            #pragma unroll
            for (int db = 0; db < 4; db++) {
                #pragma unroll
                for (int rq = 0; rq < 4; rq++) {
                    int d0 = db * 32 + rq * 8 + hh * 4;
                    float* dst0 = Obuf + r * OROW + d0;
                    float* dst1 = Obuf + (32 + r) * OROW + d0;
                    f32x4 v0 = { acc0[db][rq*4+0], acc0[db][rq*4+1], acc0[db][rq*4+2], acc0[db][rq*4+3] };
                    f32x4 v1 = { acc1[db][rq*4+0], acc1[db][rq*4+1], acc1[db][rq*4+2], acc1[db][rq*4+3] };
                    if (j > 0) {
                        v0 += *(const f32x4*)(const void*)dst0;
                        v1 += *(const f32x4*)(const void*)dst1;
                    }
                    *(f32x4*)(void*)dst0 = v0;
                    *(f32x4*)(void*)dst1 = v1;
                }
            }
        }
        __syncthreads();
    }

    // coalesced final store: thread t -> row q2 = t>>3, 16 floats at (t&7)*16
    int q2 = t >> 3;
    float lt = 0.f;
    #pragma unroll
    for (int j = 0; j < GROUPS; j++) lt += Lx[j][q2];
    float inv = 1.0f / lt;
    const float* srow = Obuf + q2 * OROW + (t & 7) * 16;
    float* orow = out + ((size_t)b * NSEQ + (size_t)qblk * 64 + q2) * DHEAD + (t & 7) * 16;
    #pragma unroll
    for (int k = 0; k < 4; k++) {
        f32x4 v = *(const f32x4*)(const void*)(srow + k * 4);
        v *= inv;
        *(f32x4*)(void*)(orow + k * 4) = v;
    }
}

extern "C" void kernel_launch(void* const* d_in, const int* in_sizes, int n_in,
                              void* d_out, int out_size, void* d_ws, size_t ws_size,
                              hipStream_t stream) {
    (void)in_sizes; (void)n_in; (void)out_size; (void)ws_size;
    const float* x = (const float*)d_in[0];
    float* out = (float*)d_out;
    char* Kp8 = (char*)d_ws;                                   // 2 MB fp8 K/Q fragments
    char* Vp  = Kp8 + (size_t)BATCH * NKT * KT8_B;             // 4 MB bf16 V^T fragments
    prep_kernel<<<BATCH * NKT, 256, 0, stream>>>(x, Kp8, Vp);
    attn_kernel<<<BATCH * (NSEQ / 64), 512, 0, stream>>>(Kp8, Vp, out);
}

// Round 15
// 49.206 us; speedup vs baseline: 2.3265x; 2.3265x over previous
//
#include <hip/hip_runtime.h>
#include <stdint.h>

typedef __bf16 bf16;
typedef bf16 bf16x8 __attribute__((ext_vector_type(8)));
typedef float f32x4 __attribute__((ext_vector_type(4)));
typedef float f32x16 __attribute__((ext_vector_type(16)));
typedef uint32_t u32;
typedef uint16_t u16;
typedef int64_t i64;
typedef i64 i64x2 __attribute__((ext_vector_type(2)));
typedef u32 u32x4 __attribute__((ext_vector_type(4)));

#define BATCH 4
#define NSEQ  4096
#define DHEAD 128
#define GROUPS 4                  // kv-split groups = waves per block
#define KB    32
#define KVSPAN (NSEQ/GROUPS)      // 1024
#define NITER  (KVSPAN/KB)        // 32
#define NKT    (NSEQ/KB)          // 128 tiles per batch
#define KT8_B  4096               // fp8 K tile bytes
#define VT_B   8192               // bf16 V^T tile bytes
#define LOG2E 1.44269504088896340736f
#define OROW  136                 // epilogue Obuf row stride (floats)

__device__ __forceinline__ u16 f2bf(float f) {
    u32 u = __builtin_bit_cast(u32, f);
    u += 0x7fff + ((u >> 16) & 1);   // RNE
    return (u16)(u >> 16);
}

// f32 -> OCP e4m3fn, RNE
__device__ __forceinline__ u32 f2fp8(float f) {
    u32 u = __builtin_bit_cast(u32, f);
    u32 sgn = (u >> 24) & 0x80;
    float af = fabsf(f);
    if (af < 0x1.0p-6f) {
        u32 m = (u32)rintf(af * 512.0f);
        return sgn | m;
    }
    u32 au = u & 0x7FFFFFFF;
    au += 0x7FFFF + ((au >> 20) & 1);
    u32 e = au >> 23;
    if (e > 135) { e = 135; au = (135u << 23) | (6u << 20); }
    u32 m3 = (au >> 20) & 7;
    return sgn | ((e - 120) << 3) | m3;
}

// |e4m3fn| -> f32 (sign dropped; used only for squaring)
__device__ __forceinline__ float dfp8(u32 c) {
    u32 a = c & 0x7F;
    u32 e = a >> 3, m = a & 7;
    float norm = __builtin_bit_cast(float, ((e + 120) << 23) | (m << 20));
    float den  = (float)m * 0x1.0p-9f;
    return e ? norm : den;
}

// ---------------- prep: fp32 x -> fp8-packed Kp8 (K/Q fragments) + bf16 Vp ----------------
__global__ __launch_bounds__(256) void prep_kernel(const float* __restrict__ x,
                                                   char* __restrict__ Kp8,
                                                   char* __restrict__ Vp) {
    __shared__ float lds[32][132];
    int bid = blockIdx.x;            // 512 blocks = b(4) x kt(128)
    int b = bid >> 7, kt = bid & 127;
    int t = threadIdx.x;
    const float* xt = x + ((size_t)b * NSEQ + kt * 32) * DHEAD;
    #pragma unroll
    for (int j = 0; j < 16; j++) {
        int idx = t + j * 256;
        int r = idx >> 7, c = idx & 127;
        lds[r][c] = xt[r * DHEAD + c];
    }
    __syncthreads();
    // K fp8 slot: one 16B slot per thread (t = dcp*64 + hh*32 + r)
    {
        int dcp = t >> 6, hh = (t >> 5) & 1, r = t & 31;
        u32 w[4];
        #pragma unroll
        for (int b8 = 0; b8 < 2; b8++) {
            #pragma unroll
            for (int half = 0; half < 2; half++) {
                u32 acc = 0;
                #pragma unroll
                for (int i = 0; i < 4; i++) {
                    float f = lds[r][dcp * 32 + b8 * 16 + hh * 8 + half * 4 + i];
                    acc |= f2fp8(f) << (8 * i);
                }
                w[b8 * 2 + half] = acc;
            }
        }
        u32x4 wv = {w[0], w[1], w[2], w[3]};
        *(u32x4*)(void*)(Kp8 + (size_t)(b * NKT + kt) * KT8_B + t * 16) = wv;
    }
    // V bf16 slots: two per thread
    char* vout = Vp + (size_t)(b * NKT + kt) * VT_B;
    #pragma unroll
    for (int j = 0; j < 2; j++) {
        int slot = t + j * 256;
        int s = slot >> 8, db = (slot >> 6) & 3, hh = (slot >> 5) & 1, r = slot & 31;
        u16 tmp[8];
        #pragma unroll
        for (int i = 0; i < 8; i++) tmp[i] = f2bf(lds[s * 16 + hh * 8 + i][db * 32 + r]);
        *(bf16x8*)(void*)(vout + slot * 16) = *(const bf16x8*)(const void*)tmp;
    }
}

// ---------------- flash attention: fused dual-q-tile, hand-interleaved ILP ----------------
// 256 blocks x 4 waves (1 wave/SIMD); each wave = one kv-group, BOTH 32-row q-tiles.
// attn_tile2 interleaves the two independent q-tile streams op-by-op: QK MFMAs
// alternate between the two accumulate chains (hides MFMA chain latency), softmax
// and pack interleave on VALU, PV alternates acc0/acc1.
__device__ __forceinline__ void load_k8(u32x4 (&k)[4], const char* p) {
    #pragma unroll
    for (int j = 0; j < 4; j++)
        k[j] = *(const u32x4*)(const void*)(p + j * 1024);
}

__device__ __forceinline__ void load_v(bf16x8 (&v)[8], const char* p) {
    #pragma unroll
    for (int db = 0; db < 4; db++) {
        v[2*db]   = *(const bf16x8*)(const void*)(p + db * 1024);          // s=0
        v[2*db+1] = *(const bf16x8*)(const void*)(p + 4096 + db * 1024);   // s=1
    }
}

__device__ __forceinline__ u32 packbf(float lo, float hi) {
    return __builtin_amdgcn_perm(__builtin_bit_cast(u32, hi),
                                 __builtin_bit_cast(u32, lo), 0x07060302u);
}

__device__ __forceinline__ void attn_tile2(const u32x4 (&k8)[4], const bf16x8 (&vf)[8],
                                           const u32x4 (&q80)[4], const u32x4 (&q81)[4],
                                           f32x16 (&acc0)[4], f32x16 (&acc1)[4],
                                           float diagL0, float diagL1,
                                           float& lsum0, float& lsum1) {
    f32x16 zz = {0.f,0.f,0.f,0.f,0.f,0.f,0.f,0.f,0.f,0.f,0.f,0.f,0.f,0.f,0.f,0.f};
    // QK^T both q-tiles: two independent MFMA chains, alternated
    f32x16 s0 = zz, s1 = zz;
    #pragma unroll
    for (int j = 0; j < 4; j++) {
        i64x2 kp  = __builtin_bit_cast(i64x2, k8[j]);
        i64x2 qp0 = __builtin_bit_cast(i64x2, q80[j]);
        i64x2 qp1 = __builtin_bit_cast(i64x2, q81[j]);
        s0 = __builtin_amdgcn_mfma_f32_32x32x16_fp8_fp8(kp[0], qp0[0], s0, 0, 0, 0);
        s1 = __builtin_amdgcn_mfma_f32_32x32x16_fp8_fp8(kp[0], qp1[0], s1, 0, 0, 0);
        s0 = __builtin_amdgcn_mfma_f32_32x32x16_fp8_fp8(kp[1], qp0[1], s0, 0, 0, 0);
        s1 = __builtin_amdgcn_mfma_f32_32x32x16_fp8_fp8(kp[1], qp1[1], s1, 0, 0, 0);
    }

    // softmax both streams, interleaved on VALU
    float p0[16], p1[16];
    #pragma unroll
    for (int i = 0; i < 16; i++) {
        p0[i] = __builtin_amdgcn_exp2f(s0[i] * LOG2E - diagL0);
        p1[i] = __builtin_amdgcn_exp2f(s1[i] * LOG2E - diagL1);
    }

    // pack both streams -> PV B-fragments (interleaved)
    u32 a01 = packbf(p0[0],  p0[1]),  b01 = packbf(p1[0],  p1[1]);
    u32 a23 = packbf(p0[2],  p0[3]),  b23 = packbf(p1[2],  p1[3]);
    u32 a45 = packbf(p0[4],  p0[5]),  b45 = packbf(p1[4],  p1[5]);
    u32 a67 = packbf(p0[6],  p0[7]),  b67 = packbf(p1[6],  p1[7]);
    u32 a89 = packbf(p0[8],  p0[9]),  b89 = packbf(p1[8],  p1[9]);
    u32 aAB = packbf(p0[10], p0[11]), bAB = packbf(p1[10], p1[11]);
    u32 aCD = packbf(p0[12], p0[13]), bCD = packbf(p1[12], p1[13]);
    u32 aEF = packbf(p0[14], p0[15]), bEF = packbf(p1[14], p1[15]);
    auto sA0 = __builtin_amdgcn_permlane32_swap(a01, a45, false, false);
    auto sB0 = __builtin_amdgcn_permlane32_swap(a23, a67, false, false);
    auto sC0 = __builtin_amdgcn_permlane32_swap(a89, aCD, false, false);
    auto sD0 = __builtin_amdgcn_permlane32_swap(aAB, aEF, false, false);
    auto sA1 = __builtin_amdgcn_permlane32_swap(b01, b45, false, false);
    auto sB1 = __builtin_amdgcn_permlane32_swap(b23, b67, false, false);
    auto sC1 = __builtin_amdgcn_permlane32_swap(b89, bCD, false, false);
    auto sD1 = __builtin_amdgcn_permlane32_swap(bAB, bEF, false, false);
    bf16x8 p00 = __builtin_bit_cast(bf16x8, (u32x4){sA0[0], sB0[0], sA0[1], sB0[1]});
    bf16x8 p01 = __builtin_bit_cast(bf16x8, (u32x4){sC0[0], sD0[0], sC0[1], sD0[1]});
    bf16x8 p10 = __builtin_bit_cast(bf16x8, (u32x4){sA1[0], sB1[0], sA1[1], sB1[1]});
    bf16x8 p11 = __builtin_bit_cast(bf16x8, (u32x4){sC1[0], sD1[0], sC1[1], sD1[1]});

    // PV both q-tiles: 16 MFMAs, 8 independent chains, alternated
    #pragma unroll
    for (int db = 0; db < 4; db++) {
        acc0[db] = __builtin_amdgcn_mfma_f32_32x32x16_bf16(vf[2*db],     p00, acc0[db], 0, 0, 0);
        acc1[db] = __builtin_amdgcn_mfma_f32_32x32x16_bf16(vf[2*db],     p10, acc1[db], 0, 0, 0);
        acc0[db] = __builtin_amdgcn_mfma_f32_32x32x16_bf16(vf[2*db + 1], p01, acc0[db], 0, 0, 0);
        acc1[db] = __builtin_amdgcn_mfma_f32_32x32x16_bf16(vf[2*db + 1], p11, acc1[db], 0, 0, 0);
    }

    // lsum trees (off the PV critical path; fills MFMA shadow)
    float t0[8], t1[8];
    #pragma unroll
    for (int i = 0; i < 8; i++) { t0[i] = p0[i] + p0[i + 8]; t1[i] = p1[i] + p1[i + 8]; }
    #pragma unroll
    for (int i = 0; i < 4; i++) { t0[i] += t0[i + 4]; t1[i] += t1[i + 4]; }
    lsum0 += (t0[0] + t0[1]) + (t0[2] + t0[3]);
    lsum1 += (t1[0] + t1[1]) + (t1[2] + t1[3]);
}

__global__ __launch_bounds__(256, 1) void attn_kernel(const char* __restrict__ Kp8,
                                                      const char* __restrict__ Vp,
                                                      float* __restrict__ out) {
    __shared__ float Obuf[64 * OROW];          // 34.8 KB epilogue combine buffer
    __shared__ float Lx[GROUPS][64];

    int bid = blockIdx.x;            // 256 blocks, 1/CU (4 waves = 1/SIMD)
    int xcd = bid & 7, pos = bid >> 3;
    int b    = xcd >> 1;             // 2 XCDs per batch -> batch packed data L2-resident
    int qblk = pos + ((xcd & 1) << 5);

    int t = threadIdx.x;
    int w = t >> 6, l = t & 63;
    int grp = w;                     // each wave is one kv-group, owns all 64 q-rows
    int r  = l & 31;                 // lane row (m/n index)
    int hh = l >> 5;                 // k-half

    const char* Kpb = Kp8 + (size_t)b * NKT * KT8_B + (size_t)l * 16;
    const char* Vpb = Vp  + (size_t)b * NKT * VT_B  + (size_t)l * 16;

    // Q fragments for both q-tiles (fp8, same packing as K)
    u32x4 q0[4], q1[4];
    load_k8(q0, Kpb + (size_t)(qblk * 2)     * KT8_B);
    load_k8(q1, Kpb + (size_t)(qblk * 2 + 1) * KT8_B);

    // diag shift C = fp8-exact ||q||^2 (decode-square-sum own half + cross-half add)
    float dsq0 = 0.f, dsq1 = 0.f;
    #pragma unroll
    for (int j = 0; j < 4; j++) {
        #pragma unroll
        for (int wv = 0; wv < 4; wv++) {
            u32 w0 = q0[j][wv], w1 = q1[j][wv];
            #pragma unroll
            for (int by = 0; by < 4; by++) {
                float v0 = dfp8(w0 >> (8 * by));
                float v1 = dfp8(w1 >> (8 * by));
                dsq0 += v0 * v0;
                dsq1 += v1 * v1;
            }
        }
    }
    dsq0 += __shfl_xor(dsq0, 32);
    dsq1 += __shfl_xor(dsq1, 32);
    float diagL0 = dsq0 * LOG2E;
    float diagL1 = dsq1 * LOG2E;

    f32x16 zz = {0.f,0.f,0.f,0.f,0.f,0.f,0.f,0.f,0.f,0.f,0.f,0.f,0.f,0.f,0.f,0.f};
    f32x16 acc0[4], acc1[4];         // out^T: d = db*32+(reg&3)+8*(reg>>2)+4*hh, q = qt*32+r
    #pragma unroll
    for (int i = 0; i < 4; i++) { acc0[i] = zz; acc1[i] = zz; }
    float lsum0 = 0.f, lsum1 = 0.f;

    int kt0 = grp * NITER;           // this group's 32 tiles
    u32x4 kA[4], kB[4];
    bf16x8 vA[8], vB[8];
    load_k8(kA, Kpb + (size_t)kt0 * KT8_B);
    load_v(vA, Vpb + (size_t)kt0 * VT_B);
    for (int it = 0; it < NITER; it += 2) {
        int kt = kt0 + it;
        load_k8(kB, Kpb + (size_t)(kt + 1) * KT8_B);          // prefetch K,V tile it+1
        load_v(vB, Vpb + (size_t)(kt + 1) * VT_B);
        attn_tile2(kA, vA, q0, q1, acc0, acc1, diagL0, diagL1, lsum0, lsum1);
        if (it + 2 < NITER) {
            load_k8(kA, Kpb + (size_t)(kt + 2) * KT8_B);      // prefetch K,V tile it+2
            load_v(vA, Vpb + (size_t)(kt + 2) * VT_B);
        }
        attn_tile2(kB, vB, q0, q1, acc0, acc1, diagL0, diagL1, lsum0, lsum1);
    }

    // ---- combine 4 kv-groups (shared shift per row -> plain sums) ----
    lsum0 += __shfl_xor(lsum0, 32);
    lsum1 += __shfl_xor(lsum1, 32);
    if (l < 32) { Lx[grp][r] = lsum0; Lx[grp][32 + r] = lsum1; }
    __syncthreads();

    #pragma unroll
    for (int j = 0; j < GROUPS; j++) {
        if (grp == j) {
            #pragma unroll
            for (int db = 0; db < 4; db++) {
                #pragma unroll
                for (int rq = 0; rq < 4; rq++) {
                    int d0 = db * 32 + rq * 8 + hh * 4;
                    float* dst0 = Obuf + r * OROW + d0;
                    float* dst1 = Obuf + (32 + r) * OROW + d0;
                    f32x4 v0 = { acc0[db][rq*4+0], acc0[db][rq*4+1], acc0[db][rq*4+2], acc0[db][rq*4+3] };
                    f32x4 v1 = { acc1[db][rq*4+0], acc1[db][rq*4+1], acc1[db][rq*4+2], acc1[db][rq*4+3] };
                    if (j > 0) {
                        v0 += *(const f32x4*)(const void*)dst0;
                        v1 += *(const f32x4*)(const void*)dst1;
                    }
                    *(f32x4*)(void*)dst0 = v0;
                    *(f32x4*)(void*)dst1 = v1;
                }
            }
        }
        __syncthreads();
    }

    // coalesced final store: thread t -> row q2 = t>>2, 32 floats at (t&3)*32
    int q2 = t >> 2;
    int c0 = (t & 3) * 32;
    float lt = Lx[0][q2] + Lx[1][q2] + Lx[2][q2] + Lx[3][q2];
    float inv = 1.0f / lt;
    const float* srow = Obuf + q2 * OROW + c0;
    float* orow = out + ((size_t)b * NSEQ + (size_t)qblk * 64 + q2) * DHEAD + c0;
    #pragma unroll
    for (int k = 0; k < 8; k++) {
        f32x4 v = *(const f32x4*)(const void*)(srow + k * 4);
        v *= inv;
        *(f32x4*)(void*)(orow + k * 4) = v;
    }
}

extern "C" void kernel_launch(void* const* d_in, const int* in_sizes, int n_in,
                              void* d_out, int out_size, void* d_ws, size_t ws_size,
                              hipStream_t stream) {
    (void)in_sizes; (void)n_in; (void)out_size; (void)ws_size;
    const float* x = (const float*)d_in[0];
    float* out = (float*)d_out;
    char* Kp8 = (char*)d_ws;                                   // 2 MB fp8 K/Q fragments
    char* Vp  = Kp8 + (size_t)BATCH * NKT * KT8_B;             // 4 MB bf16 V^T fragments
    prep_kernel<<<BATCH * NKT, 256, 0, stream>>>(x, Kp8, Vp);
    attn_kernel<<<BATCH * (NSEQ / 64), 256, 0, stream>>>(Kp8, Vp, out);
}